// Round 4
// baseline (178.573 us; speedup 1.0000x reference)
//
#include <hip/hip_runtime.h>
#include <math.h>

#define ROWN 10000
#define COLN 4096
#define DIM 16
#define EN 1000000
#define BIGF 100000.0f

// per-column record: 48 float4 (768 B)
//  [0]        = (1, t, t^2/2, t^3/6)
//  [1..40]    = L^T ragged quads: for k=0..15, quads q=k/4..3, elem j = L[4q+j][k]
//  [41..44]   = z_cols[c] (16 floats)
//  [45]       = (gamma_col, 0, 0, 0)
#define RECQ 48
#define RECF (RECQ * 4)

#define NBT 40       // z-transpose blocks (250 rows each)
#define RPT 250      // rows per transpose block
#define NBH 64       // histogram chunks
#define CHH 15625    // EN / NBH exact
#define NBS 250      // scatter chunks
#define CHS 4000     // EN / NBS exact

#define CPB 4              // columns per edge block
#define EBLK (COLN / CPB)  // 1024 edge blocks

struct Ctrl { int done; int pad; };

// ragged L^T quad tables
__constant__ int QK[40] = {0,0,0,0, 1,1,1,1, 2,2,2,2, 3,3,3,3,
                           4,4,4, 5,5,5, 6,6,6, 7,7,7,
                           8,8, 9,9, 10,10, 11,11, 12, 13, 14, 15};
__constant__ int QQ[40] = {0,1,2,3, 0,1,2,3, 0,1,2,3, 0,1,2,3,
                           1,2,3, 1,2,3, 1,2,3, 1,2,3,
                           2,3, 2,3, 2,3, 2,3, 3, 3, 3, 3};

// offset of k's first quad within the ragged block (compile-time foldable)
__host__ __device__ __forceinline__ constexpr int offk(int k) {
    return (k < 4) ? k * 4
         : (k < 8) ? 16 + (k - 4) * 3
         : (k < 12) ? 28 + (k - 8) * 2
         : 36 + (k - 12);
}

// ---------- fused init: z-transpose + chunk histogram + column records -----
// gcnt must be zeroed before this kernel.
__global__ __launch_bounds__(256) void init3(
    const float* __restrict__ z_rows, const float* __restrict__ z_cols,
    const float* __restrict__ gamma_cols, const float* __restrict__ L,
    const float* __restrict__ col_times, const int* __restrict__ col_idx_list,
    float* __restrict__ rec, float* __restrict__ zt,
    const int* __restrict__ mc, int* __restrict__ gcnt)
{
    const int tid = threadIdx.x;
    if (blockIdx.x < NBT) {
        // ---- transpose z_rows [4][ROW][16] -> zt [ROW][4][16] ----
        const int r0 = blockIdx.x * RPT;
        const size_t SL = (size_t)ROWN * DIM;
        float4* dst = (float4*)zt;
        #pragma unroll
        for (int v = 0; v < 4; ++v) {
            const float4* src = (const float4*)(z_rows + (size_t)v * SL
                                                + (size_t)r0 * DIM);
            for (int idx = tid; idx < RPT * 4; idx += 256) {
                const int r = idx >> 2, q = idx & 3;
                dst[(size_t)(r0 + r) * 16 + v * 4 + q] = src[idx];
            }
        }
    } else if (blockIdx.x < NBT + NBH) {
        // ---- per-chunk histogram of mat_cols ----
        __shared__ int h[COLN];
        const int b = blockIdx.x - NBT;
        for (int i = tid; i < COLN; i += 256) h[i] = 0;
        __syncthreads();
        const int lo = b * CHH, hi = min(lo + CHH, EN);
        for (int e = lo + tid; e < hi; e += 256)
            atomicAdd(&h[mc[e]], 1);
        __syncthreads();
        for (int i = tid; i < COLN; i += 256) {
            int v = h[i];
            if (v) atomicAdd(&gcnt[i], v);
        }
    } else {
        // ---- per-column record ----
        __shared__ float Lsh[DIM][DIM + 1];
        const int c = blockIdx.x - (NBT + NBH);
        const int cidx = col_idx_list[c];
        Lsh[tid >> 4][tid & 15] = L[(size_t)cidx * 256 + tid];
        __syncthreads();

        float4* r = (float4*)(rec + (size_t)c * RECF);
        if (tid < 40) {
            const int k = QK[tid];
            const int d = 4 * QQ[tid];
            r[1 + tid] = make_float4(Lsh[d][k], Lsh[d+1][k], Lsh[d+2][k], Lsh[d+3][k]);
        } else if (tid < 44) {
            const int j = tid - 40;
            const float* zp = z_cols + (size_t)c * DIM + 4 * j;
            r[41 + j] = make_float4(zp[0], zp[1], zp[2], zp[3]);
        } else if (tid == 44) {
            const float t = col_times[c];
            r[0]  = make_float4(1.0f, t, 0.5f * t * t, t * t * t * (1.0f / 6.0f));
            r[45] = make_float4(gamma_cols[c], 0.0f, 0.0f, 0.0f);
        }
    }
}

// ---------- scatter with fused redundant scan -------------------------------
__global__ __launch_bounds__(512) void scatter4(
    const int* __restrict__ mr, const int* __restrict__ mc,
    const int* __restrict__ yy, const int* __restrict__ gcnt,
    int* __restrict__ gcur, int* __restrict__ gbase,
    int* __restrict__ packed)
{
    __shared__ int bases[COLN];
    __shared__ int lh[COLN];
    __shared__ int sums[512];
    const int tid = threadIdx.x;

    // tight exclusive scan of the 4096 counts (redundant per block, cheap)
    int s = 0;
    #pragma unroll
    for (int i = 0; i < 8; ++i) {
        int c = tid * 8 + i;
        int v = gcnt[c];
        bases[c] = v;
        s += v;
    }
    sums[tid] = s;
    __syncthreads();
    for (int off = 1; off < 512; off <<= 1) {
        int v = (tid >= off) ? sums[tid - off] : 0;
        __syncthreads();
        sums[tid] += v;
        __syncthreads();
    }
    int run = (tid == 0) ? 0 : sums[tid - 1];
    #pragma unroll
    for (int i = 0; i < 8; ++i) {
        int c = tid * 8 + i;
        int v = bases[c];
        bases[c] = run;
        run += v;
    }
    if (blockIdx.x == 0) {
        #pragma unroll
        for (int i = 0; i < 8; ++i) { int c = tid * 8 + i; gbase[c] = bases[c]; }
        if (tid == 511) gbase[COLN] = run;   // sentinel = EN
    }

    // per-chunk local histogram
    for (int i = tid; i < COLN; i += 512) lh[i] = 0;
    __syncthreads();
    const int b = blockIdx.x;
    const int lo = b * CHS, hi = min(lo + CHS, EN);
    for (int e = lo + tid; e < hi; e += 512)
        atomicAdd(&lh[mc[e]], 1);
    __syncthreads();

    // reserve global ranges (gcur = offset-from-base, zeroed)
    for (int i = tid; i < COLN; i += 512) {
        int cntl = lh[i];
        if (cntl) lh[i] = bases[i] + atomicAdd(&gcur[i], cntl);
    }
    __syncthreads();

    // place: 14 bits row + 3 bits y + 2 bits local column (c & 3)
    for (int e = lo + tid; e < hi; e += 512) {
        int c = mc[e];
        int pos = atomicAdd(&lh[c], 1);
        packed[pos] = mr[e] | (yy[e] << 14) | ((c & 3) << 17);
    }
}

// log( Phi(hi) - Phi(lo) ), cancellation-free, branch-light, always finite.
__device__ __forceinline__ float log_cdf_diff_f(float hi, float lo) {
    const float r = 0.70710678118654752440f;
    if (hi + lo < 0.0f) { float t = hi; hi = -lo; lo = -t; }
    float d = erfcf(lo * r) - erfcf(hi * r);
    return logf(0.5f * fmaxf(d, 1e-37f));
}

// ---------- edge kernel: 4 columns/block, prefetch, fused finalize ---------
__global__ __launch_bounds__(256, 4) void edge5(
    const float* __restrict__ zt, const float* __restrict__ gamma_rows,
    const float4* __restrict__ rec4, const float* __restrict__ b,
    const float* __restrict__ sigma, const int* __restrict__ packed,
    const int* __restrict__ gbase, Ctrl* __restrict__ ctrl,
    double* __restrict__ bsum, float* __restrict__ out)
{
    __shared__ float4 R[CPB * RECQ];    // 3072 B: 4 column records
    __shared__ float th[6];
    __shared__ double wsum[4];
    __shared__ int lastf;
    const int tid = threadIdx.x;
    const int c0 = blockIdx.x * CPB;
    if (tid < CPB * RECQ) R[tid] = rec4[(size_t)c0 * RECQ + tid];
    if (tid == 0) { th[0] = -BIGF; th[5] = BIGF; }
    if (tid < 4)  th[1 + tid] = b[tid];
    __syncthreads();

    const float inv_s = 1.0f / sigma[0];
    const int base = gbase[c0];
    const int end  = gbase[c0 + CPB];    // sentinel makes c0+CPB==COLN valid

    double acc = 0.0;
    int i = base + tid;
    int p = 0;
    if (i < end) p = packed[i];          // prime the pipeline
    for (; i < end; i += 256) {
        const int row = p & 0x3FFF;
        const int yv  = (p >> 14) & 7;
        const int cl  = (p >> 17) & 3;
        const float ga = gamma_rows[row];                 // issues early
        const float4* __restrict__ zp = (const float4*)(zt + (size_t)row * 64);

        // batch all 16 z loads (256B contiguous) before any use
        float4 a[16];
        #pragma unroll
        for (int j = 0; j < 16; ++j) a[j] = zp[j];

        // prefetch next packed entry (hides its L2 trip under this iteration)
        int pn = 0;
        if (i + 256 < end) pn = packed[i + 256];

        const float4* __restrict__ Rc = &R[cl * RECQ];
        const float4 t0 = Rc[0];
        const float tp1 = t0.y, tp2 = t0.z, tp3 = t0.w;

        // delta[d] = sum_v a[v*4+q]*tp[v] - zc[d]
        float d_[DIM];
        #pragma unroll
        for (int q = 0; q < 4; ++q) {
            const float4 zc = Rc[41 + q];
            d_[4*q+0] = fmaf(a[12+q].x, tp3, fmaf(a[8+q].x, tp2, fmaf(a[4+q].x, tp1, a[q].x))) - zc.x;
            d_[4*q+1] = fmaf(a[12+q].y, tp3, fmaf(a[8+q].y, tp2, fmaf(a[4+q].y, tp1, a[q].y))) - zc.y;
            d_[4*q+2] = fmaf(a[12+q].z, tp3, fmaf(a[8+q].z, tp2, fmaf(a[4+q].z, tp1, a[q].z))) - zc.z;
            d_[4*q+3] = fmaf(a[12+q].w, tp3, fmaf(a[8+q].w, tp2, fmaf(a[4+q].w, tp1, a[q].w))) - zc.w;
        }

        // nsq = || delta^T L ||^2, ragged lower-triangular at quad granularity
        float nsq = 0.0f;
        #pragma unroll
        for (int k = 0; k < DIM; ++k) {
            const int q0 = k >> 2;
            float t = 0.0f;
            #pragma unroll
            for (int q = q0; q < 4; ++q) {
                const float4 lv = Rc[1 + offk(k) + (q - q0)];
                t = fmaf(lv.x, d_[4*q+0],
                    fmaf(lv.y, d_[4*q+1],
                    fmaf(lv.z, d_[4*q+2],
                    fmaf(lv.w, d_[4*q+3], t))));
            }
            nsq = fmaf(t, t, nsq);
        }

        const float f = ga + Rc[45].x - sqrtf(nsq);
        acc += (double)log_cdf_diff_f((th[yv] - f) * inv_s,
                                      (th[yv - 1] - f) * inv_s);
        p = pn;
    }

    #pragma unroll
    for (int off = 32; off > 0; off >>= 1) acc += __shfl_down(acc, off, 64);
    const int lane = tid & 63;
    const int wid  = tid >> 6;
    if (lane == 0) wsum[wid] = acc;
    __syncthreads();
    if (tid == 0) {
        bsum[blockIdx.x] = wsum[0] + wsum[1] + wsum[2] + wsum[3];  // plain store
        __threadfence();
        const int old = atomicAdd(&ctrl->done, 1);   // own cacheline, low contention
        lastf = (old == EBLK - 1);
    }
    __syncthreads();
    if (lastf) {
        __threadfence();
        double a2 = 0.0;
        #pragma unroll
        for (int j = 0; j < EBLK / 256; ++j) a2 += bsum[tid + j * 256];
        #pragma unroll
        for (int off = 32; off > 0; off >>= 1) a2 += __shfl_down(a2, off, 64);
        if (lane == 0) wsum[wid] = a2;
        __syncthreads();
        if (tid == 0) out[0] = -(float)(wsum[0] + wsum[1] + wsum[2] + wsum[3]);
    }
}

extern "C" void kernel_launch(void* const* d_in, const int* in_sizes, int n_in,
                              void* d_out, int out_size, void* d_ws, size_t ws_size,
                              hipStream_t stream) {
    const float* z_rows       = (const float*)d_in[0];
    const float* z_cols       = (const float*)d_in[1];
    const float* gamma_rows   = (const float*)d_in[2];
    const float* gamma_cols   = (const float*)d_in[3];
    const float* L            = (const float*)d_in[4];
    const float* b            = (const float*)d_in[5];
    const float* sigma        = (const float*)d_in[6];
    const float* col_times    = (const float*)d_in[7];
    const int*   mat_rows     = (const int*)d_in[8];
    const int*   mat_cols     = (const int*)d_in[9];
    const int*   y            = (const int*)d_in[10];
    const int*   col_idx_list = (const int*)d_in[11];

    // workspace layout (16B aligned):
    //   rec   : 3,145,728 B   @ 0
    //   zt    : 2,560,000 B   @ 3,145,728
    //   gcnt  : 16,384 B      @ 5,705,728   \
    //   gcur  : 16,384 B      @ 5,722,112    } one memset
    //   ctrl  : 128 B         @ 5,738,496   /
    //   gbase : 16,448 B      @ 5,738,624   (4097 ints incl. sentinel)
    //   bsum  : 8,192 B       @ 5,755,072
    //   pk    : 4,000,000 B   @ 5,763,264   (total 9,763,264 B)
    char* ws = (char*)d_ws;
    float*  rec   = (float*)ws;
    float*  zt    = (float*)(ws + 3145728);
    int*    gcnt  = (int*)(ws + 5705728);
    int*    gcur  = (int*)(ws + 5722112);
    Ctrl*   ctrl  = (Ctrl*)(ws + 5738496);
    int*    gbase = (int*)(ws + 5738624);
    double* bsum  = (double*)(ws + 5755072);
    int*    pk    = (int*)(ws + 5763264);

    hipMemsetAsync(gcnt, 0, 2 * 16384 + 128, stream);   // counts + cursors + ctrl
    init3<<<NBT + NBH + COLN, 256, 0, stream>>>(
        z_rows, z_cols, gamma_cols, L, col_times, col_idx_list, rec, zt,
        mat_cols, gcnt);
    scatter4<<<NBS, 512, 0, stream>>>(mat_rows, mat_cols, y, gcnt, gcur, gbase, pk);
    edge5<<<EBLK, 256, 0, stream>>>(zt, gamma_rows, (const float4*)rec,
                                    b, sigma, pk, gbase, ctrl, bsum,
                                    (float*)d_out);
}